// Round 1
// baseline (61.359 us; speedup 1.0000x reference)
//
#include <hip/hip_runtime.h>
#include <hip/hip_bf16.h>

// YOLO layer decode: x (16, 340, 76, 76) f32 -> out (16, 4*76*76, 85) f32.
// Per (b, a, y) slab: transpose [c=85][x=76] -> [x=76][c=85] via LDS,
// applying sigmoid/exp transforms on load.

constexpr int BS = 16;
constexpr int NA = 4;
constexpr int NC = 85;
constexpr int FY = 76;
constexpr int FX = 76;
constexpr int PLANE = FY * FX;        // 5776
constexpr int TILE  = NC * FX;        // 6460 floats per slab
constexpr float STRIDE_F = 8.0f;

__global__ __launch_bounds__(256)
void yolo_decode_kernel(const float* __restrict__ x,
                        const float* __restrict__ anchors,
                        float* __restrict__ out) {
    __shared__ float lds[TILE];       // [x][c], flat: x*NC + c  (25840 B)

    const int blk = blockIdx.x;       // (b*NA + a)*FY + y
    const int y   = blk % FY;
    const int ba  = blk / FY;         // b*NA + a
    const int a   = ba % NA;

    const float ax = anchors[a * 2 + 0] * STRIDE_F;
    const float ay = anchors[a * 2 + 1] * STRIDE_F;
    const float yf = (float)y;

    const float* __restrict__ inbase = x + (size_t)ba * NC * PLANE + (size_t)y * FX;

    // Load + transform: i = c*FX + xi, coalesced over xi within each row.
    for (int i = threadIdx.x; i < TILE; i += 256) {
        const int c  = i / FX;
        const int xi = i - c * FX;
        const float v = inbase[(size_t)c * PLANE + xi];
        float r;
        if (c == 0) {
            r = (1.0f / (1.0f + expf(-v)) + (float)xi) * STRIDE_F;
        } else if (c == 1) {
            r = (1.0f / (1.0f + expf(-v)) + yf) * STRIDE_F;
        } else if (c == 2) {
            r = expf(v) * ax;
        } else if (c == 3) {
            r = expf(v) * ay;
        } else {
            r = 1.0f / (1.0f + expf(-v));
        }
        lds[xi * NC + c] = r;         // stride 85 (odd) -> benign bank pattern
    }

    __syncthreads();

    // Write: contiguous 6460 floats; base 16B-aligned (6460*4 % 16 == 0).
    float4* __restrict__ outbase = (float4*)(out + (size_t)blk * TILE);
    const float4* __restrict__ ldsv = (const float4*)lds;
    for (int i = threadIdx.x; i < TILE / 4; i += 256) {   // 1615 float4s
        outbase[i] = ldsv[i];
    }
}

extern "C" void kernel_launch(void* const* d_in, const int* in_sizes, int n_in,
                              void* d_out, int out_size, void* d_ws, size_t ws_size,
                              hipStream_t stream) {
    const float* x       = (const float*)d_in[0];
    const float* anchors = (const float*)d_in[1];
    float* out           = (float*)d_out;

    const int nblocks = BS * NA * FY;   // 4864
    yolo_decode_kernel<<<nblocks, 256, 0, stream>>>(x, anchors, out);
}

// Round 3
// 56.977 us; speedup vs baseline: 1.0769x; 1.0769x over previous
//
#include <hip/hip_runtime.h>
#include <hip/hip_bf16.h>

// YOLO layer decode: x (16, 340, 76, 76) f32 -> out (16, 4*76*76, 85) f32.
// Per (b, a, y) slab: transpose [c=85][x=76] -> [x=76][c=85] via LDS,
// applying sigmoid/exp transforms on load. Fast transcendentals via
// v_exp_f32 (exp2) + v_rcp_f32 — ~1 ULP, threshold is 66.24 absmax.

constexpr int BS = 16;
constexpr int NA = 4;
constexpr int NC = 85;
constexpr int FY = 76;
constexpr int FX = 76;
constexpr int PLANE = FY * FX;        // 5776
constexpr int TILE  = NC * FX;        // 6460 floats per slab
constexpr float STRIDE_F = 8.0f;
constexpr float LOG2E = 1.4426950408889634f;

__device__ __forceinline__ float fast_sigmoid(float v) {
    // 1 / (1 + 2^(-v*log2e)) : v_mul + v_exp + v_add + v_rcp
    return __builtin_amdgcn_rcpf(1.0f + __builtin_amdgcn_exp2f(v * -LOG2E));
}

__device__ __forceinline__ float fast_exp(float v) {
    return __builtin_amdgcn_exp2f(v * LOG2E);
}

__global__ __launch_bounds__(256)
void yolo_decode_kernel(const float* __restrict__ x,
                        const float* __restrict__ anchors,
                        float* __restrict__ out) {
    __shared__ float lds[TILE];       // [x][c], flat: x*NC + c  (25840 B)

    const int blk = blockIdx.x;       // (b*NA + a)*FY + y
    const int y   = blk % FY;
    const int ba  = blk / FY;         // b*NA + a
    const int a   = ba % NA;

    const float ax = anchors[a * 2 + 0] * STRIDE_F;
    const float ay = anchors[a * 2 + 1] * STRIDE_F;
    const float yf = (float)y;

    const float* __restrict__ inbase = x + (size_t)ba * NC * PLANE + (size_t)y * FX;

    // --- Phase 1: c in [0,4) -- the 4 special rows (304 elements > 256
    // threads, so this MUST be a strided loop). ---
    for (int i = threadIdx.x; i < 4 * FX; i += 256) {
        const int c  = i / FX;
        const int xi = i - c * FX;
        const float v = inbase[(size_t)c * PLANE + xi];
        float r;
        if (c == 0) {
            r = fast_sigmoid(v) * STRIDE_F + (float)xi * STRIDE_F;
        } else if (c == 1) {
            r = fast_sigmoid(v) * STRIDE_F + yf * STRIDE_F;
        } else if (c == 2) {
            r = fast_exp(v) * ax;
        } else {
            r = fast_exp(v) * ay;
        }
        lds[xi * NC + c] = r;
    }

    // --- Phase 2: c in [4,85) -- pure sigmoid, branch-free hot loop. ---
    for (int i = 4 * FX + threadIdx.x; i < TILE; i += 256) {
        const int c  = i / FX;            // magic-mul division
        const int xi = i - c * FX;
        const float v = inbase[(size_t)c * PLANE + xi];
        lds[xi * NC + c] = fast_sigmoid(v);   // stride-85 scatter: conflict-free
    }

    __syncthreads();

    // Write: contiguous 6460 floats; base 16B-aligned (6460*4 % 16 == 0).
    float4* __restrict__ outbase = (float4*)(out + (size_t)blk * TILE);
    const float4* __restrict__ ldsv = (const float4*)lds;
    for (int i = threadIdx.x; i < TILE / 4; i += 256) {   // 1615 float4s
        outbase[i] = ldsv[i];
    }
}

extern "C" void kernel_launch(void* const* d_in, const int* in_sizes, int n_in,
                              void* d_out, int out_size, void* d_ws, size_t ws_size,
                              hipStream_t stream) {
    const float* x       = (const float*)d_in[0];
    const float* anchors = (const float*)d_in[1];
    float* out           = (float*)d_out;

    const int nblocks = BS * NA * FY;   // 4864
    yolo_decode_kernel<<<nblocks, 256, 0, stream>>>(x, anchors, out);
}

// Round 4
// 50.607 us; speedup vs baseline: 1.2125x; 1.1259x over previous
//
#include <hip/hip_runtime.h>
#include <hip/hip_bf16.h>

// YOLO layer decode: x (16, 340, 76, 76) f32 -> out (16, 4*76*76, 85) f32.
// Per (b, a, y) slab: transpose [c=85][x=76] -> [x=76][c=85] via LDS.
// float4 global loads (rows are 19 float4s, all 16B-aligned), fast
// transcendentals (v_exp_f32 + v_rcp_f32), 512-thread blocks for 32 waves/CU.

constexpr int BS = 16;
constexpr int NA = 4;
constexpr int NC = 85;
constexpr int FY = 76;
constexpr int FX = 76;
constexpr int PLANE = FY * FX;        // 5776
constexpr int TILE  = NC * FX;        // 6460 floats per slab
constexpr int ROWV  = FX / 4;         // 19 float4s per row
constexpr int NVEC  = TILE / 4;       // 1615 float4s per slab
constexpr float STRIDE_F = 8.0f;
constexpr float LOG2E = 1.4426950408889634f;

__device__ __forceinline__ float fast_sigmoid(float v) {
    return __builtin_amdgcn_rcpf(1.0f + __builtin_amdgcn_exp2f(v * -LOG2E));
}
__device__ __forceinline__ float fast_exp(float v) {
    return __builtin_amdgcn_exp2f(v * LOG2E);
}

__global__ __launch_bounds__(512)
void yolo_decode_kernel(const float* __restrict__ x,
                        const float* __restrict__ anchors,
                        float* __restrict__ out) {
    __shared__ float lds[TILE];       // [x][c], flat: x*NC + c  (25840 B)

    const int blk = blockIdx.x;       // (b*NA + a)*FY + y
    const int y   = blk % FY;
    const int ba  = blk / FY;         // b*NA + a
    const int a   = ba % NA;

    const float ax = anchors[a * 2 + 0] * STRIDE_F;
    const float ay = anchors[a * 2 + 1] * STRIDE_F;
    const float yf = (float)y;

    const float* __restrict__ inbase = x + (size_t)ba * NC * PLANE + (size_t)y * FX;
    const int tid = threadIdx.x;

    // --- Phase 1: c in [0,4): 4 rows x 19 float4s = 76 vectors, one pass. ---
    if (tid < 4 * ROWV) {
        const int c = tid / ROWV;
        const int j = tid - c * ROWV;
        const float4 v = *(const float4*)(inbase + (size_t)c * PLANE + j * 4);
        float r[4];
        const float vv[4] = {v.x, v.y, v.z, v.w};
        #pragma unroll
        for (int k = 0; k < 4; ++k) {
            const int xi = 4 * j + k;
            float rr;
            if (c == 0)      rr = fast_sigmoid(vv[k]) * STRIDE_F + (float)xi * STRIDE_F;
            else if (c == 1) rr = fast_sigmoid(vv[k]) * STRIDE_F + yf * STRIDE_F;
            else if (c == 2) rr = fast_exp(vv[k]) * ax;
            else             rr = fast_exp(vv[k]) * ay;
            r[k] = rr;
        }
        #pragma unroll
        for (int k = 0; k < 4; ++k)
            lds[(4 * j + k) * NC + c] = r[k];
    }

    // --- Phase 2: c in [4,85): 81 rows x 19 = 1539 float4s, pure sigmoid. ---
    for (int i = 4 * ROWV + tid; i < NVEC; i += 512) {
        const int c = i / ROWV;           // magic-mul division
        const int j = i - c * ROWV;
        const float4 v = *(const float4*)(inbase + (size_t)c * PLANE + j * 4);
        float* __restrict__ dst = &lds[(4 * j) * NC + c];
        dst[0 * NC] = fast_sigmoid(v.x);
        dst[1 * NC] = fast_sigmoid(v.y);
        dst[2 * NC] = fast_sigmoid(v.z);
        dst[3 * NC] = fast_sigmoid(v.w);
    }

    __syncthreads();

    // Write: contiguous 6460 floats; base 16B-aligned (6460*4 % 16 == 0).
    float4* __restrict__ outbase = (float4*)(out + (size_t)blk * TILE);
    const float4* __restrict__ ldsv = (const float4*)lds;
    for (int i = tid; i < NVEC; i += 512) {   // 1615 float4s
        outbase[i] = ldsv[i];
    }
}

extern "C" void kernel_launch(void* const* d_in, const int* in_sizes, int n_in,
                              void* d_out, int out_size, void* d_ws, size_t ws_size,
                              hipStream_t stream) {
    const float* x       = (const float*)d_in[0];
    const float* anchors = (const float*)d_in[1];
    float* out           = (float*)d_out;

    const int nblocks = BS * NA * FY;   // 4864
    yolo_decode_kernel<<<nblocks, 512, 0, stream>>>(x, anchors, out);
}